// Round 13
// baseline (482.062 us; speedup 1.0000x reference)
//
#include <hip/hip_runtime.h>
#include <hip/hip_bf16.h>
#include <type_traits>

#define TSEQ 1024
#define NB   128
#define HID  128
#define QDIM 16

typedef unsigned int  u32;
typedef unsigned short u16;
typedef float f32x2 __attribute__((ext_vector_type(2)));

// ---------------- cross-lane helpers (wave64) ----------------

template<int CTRL>
__device__ __forceinline__ int dpp_i(int x) {
  return __builtin_amdgcn_update_dpp(0, x, CTRL, 0xF, 0xF, true);
}
template<int CTRL>
__device__ __forceinline__ float dpp_f(float x) {
  return __int_as_float(dpp_i<CTRL>(__float_as_int(x)));
}

#ifdef __has_builtin
#if __has_builtin(__builtin_amdgcn_permlane16_swap) && __has_builtin(__builtin_amdgcn_permlane32_swap)
#define HAS_PLS 1
#endif
#endif
#ifndef HAS_PLS
#define HAS_PLS 0
#endif

__device__ __forceinline__ float pls16_sum(float x) {
#if HAS_PLS
  auto r = __builtin_amdgcn_permlane16_swap(__float_as_uint(x), __float_as_uint(x), false, false);
  return __uint_as_float(r[0]) + __uint_as_float(r[1]);
#else
  return x + __shfl_xor(x, 16, 64);
#endif
}
__device__ __forceinline__ float pls32_sum(float x) {
#if HAS_PLS
  auto r = __builtin_amdgcn_permlane32_swap(__float_as_uint(x), __float_as_uint(x), false, false);
  return __uint_as_float(r[0]) + __uint_as_float(r[1]);
#else
  return x + __shfl_xor(x, 32, 64);
#endif
}

__device__ __forceinline__ float rcpf(float x) { return __builtin_amdgcn_rcpf(x); }

__device__ __forceinline__ float ex2(float x) {
#if defined(__has_builtin)
#if __has_builtin(__builtin_amdgcn_exp2f)
  return __builtin_amdgcn_exp2f(x);
#else
  return exp2f(x);
#endif
#else
  return exp2f(x);
#endif
}

__device__ __forceinline__ f32x2 s2(float x) { f32x2 r; r.x = x; r.y = x; return r; }

// CNOT-ladder index map g (verified in R1-R12).
__device__ __forceinline__ int gperm(int t) {
  int u = t;
#define APPLY(c, tt) u ^= (((u >> (3 - (c))) & 1) << (3 - (tt)));
  APPLY(3, 1) APPLY(2, 0) APPLY(1, 3) APPLY(0, 2)
  APPLY(3, 0) APPLY(2, 3) APPLY(1, 2) APPLY(0, 1)
#undef APPLY
  return u;
}

// ---------------- kernel 1: xwP[b,t,j] = x[b,t,:] @ W_x[:,g(j)] + b_in[g(j)] ----------------

__global__ __launch_bounds__(256) void xw_kernel(
    const float* __restrict__ x, const float* __restrict__ W_in,
    const float* __restrict__ b_in, float* __restrict__ xw) {
  __shared__ __align__(16) float xs[16][132];
  __shared__ float wl[2048];
  __shared__ float bl[16];
  const int tid = threadIdx.x;
  const long r0 = (long)blockIdx.x * 16;
#pragma unroll
  for (int i = 0; i < 8; ++i) {
    int idx = tid + i * 256;
    xs[idx >> 7][idx & 127] = x[(r0 + (idx >> 7)) * 128 + (idx & 127)];
  }
#pragma unroll
  for (int i = 0; i < 8; ++i) {
    int idx = tid + i * 256;
    wl[idx] = W_in[2048 + idx];   // W_x = W_in[128:256, :]
  }
  if (tid < 16) bl[tid] = b_in[tid];
  __syncthreads();
  const int rr = tid >> 4, j = tid & 15;
  const int gj = gperm(j);
  float s = bl[gj];
#pragma unroll
  for (int k4 = 0; k4 < 32; ++k4) {
    float4 v = *reinterpret_cast<const float4*>(&xs[rr][k4 * 4]);
    int kb = k4 * 4;
    s = fmaf(v.x, wl[(kb + 0) * 16 + gj], s);
    s = fmaf(v.y, wl[(kb + 1) * 16 + gj], s);
    s = fmaf(v.z, wl[(kb + 2) * 16 + gj], s);
    s = fmaf(v.w, wl[(kb + 3) * 16 + gj], s);
  }
  xw[(r0 + rr) * 16 + j] = s;
}

// ---------------- kernel 2: recurrence. 256 blocks x 1 wave; all-register ----------------
// R13: Walsh transform (ebf) rebuilt rotation-native: 5 fusable dpp-add levels,
// no xor4 emulation. Component lane-signs: chi_0/chi_1 folded into gate tables
// (stable under +/-4 rotation); chi_2 via one mul of shared S3; chi_3 via premul
// of p then 4 plain ror-adds. All components rotation-direction-invariant
// (verified algebraically), so no probe needed for the Walsh. bfr keeps R12's
// direction probe. bwd bf16 store via v_cvt_pk_bf16_f32 (same RNE rounding).

__global__ __launch_bounds__(64)
__attribute__((amdgpu_waves_per_eu(1, 2)))
void qbigru_main(
    const float* __restrict__ W_in,
    const float* __restrict__ W_out,
    const float* __restrict__ b_out,
    const float* __restrict__ thr_f, const float* __restrict__ thr1_f, const float* __restrict__ thu_f,
    const float* __restrict__ thr_b, const float* __restrict__ thr1_b, const float* __restrict__ thu_b,
    const float* __restrict__ xw,
    float* __restrict__ out,
    void* __restrict__ bwdws) {
  const int tid = threadIdx.x;
  const int l4  = tid & 15;
  const int dir = blockIdx.x >> 7;
  const int b   = blockIdx.x & 127;

  // row_ror direction probe for bfr: ror:1 on the row-lane index. Wave-uniform bool.
  const int q1 = dpp_i<0x121>(l4);
  const bool dplus = (q1 == ((l4 + 1) & 15));   // true: ror:c reads lane (l+c)&15

  const float sgn2 = ((l4 >> 2) & 1) ? -1.f : 1.f;
  const float sgn3 = ((l4 >> 3) & 1) ? -1.f : 1.f;

  // Rotation-native Walsh over the 16-lane row. Input p on every lane (own col l4).
  // Outputs: n2 = sum p; e[0] = chi0(l)*W0, e[1] = chi1(l)*W1 (chi folded into
  // gate tables), e[2] = W2, e[3] = W3 (row-uniform). W_B = sum_s p(s)(-1)^{s_B}.
  auto walsh = [&](float p, float& n2, float* e) {
    float d1 = dpp_f<0xB1>(p);           // xor1 (quad_perm)
    float S1 = p + d1;
    float D1 = p - d1;                   // chi0-signed
    float u3 = p * sgn3;
    float S2 = S1 + dpp_f<0x4E>(S1);     // xor2 (quad_perm)
    float D2 = S1 - dpp_f<0x4E>(S1);     // chi1-signed
    float W0a = D1 + dpp_f<0x4E>(D1);
    float u3a = u3 + dpp_f<0x128>(u3);   // ror8
    float S3  = S2 + dpp_f<0x128>(S2);   // ror8 (== xor8)
    float D2b = D2 + dpp_f<0x128>(D2);
    float W0b = W0a + dpp_f<0x128>(W0a);
    float u3b = u3a + dpp_f<0x124>(u3a); // ror4
    float u2  = S3 * sgn2;
    n2   = S3  + dpp_f<0x124>(S3);
    e[1] = D2b + dpp_f<0x124>(D2b);
    e[0] = W0b + dpp_f<0x124>(W0b);
    e[2] = u2  + dpp_f<0x124>(u2);
    float u3c = u3b + dpp_f<0x122>(u3b); // ror2
    e[3] = u3c + dpp_f<0x121>(u3c);      // ror1
  };

  // ---- per-lane constants ----
  const float* thr  = dir ? thr_b  : thr_f;
  const float* thr1 = dir ? thr1_b : thr1_f;
  const float* thu  = dir ? thu_b  : thu_f;

  const int k0 = 2 * tid, k1 = 2 * tid + 1;   // this lane's hidden units (k == m)

  // W_h, ROTATION layout + CNOT perm folded: slot i holds column g((i + l4) & 15).
  f32x2 w0p[8], w1p[8];
#pragma unroll
  for (int i = 0; i < 8; ++i) {
    int ja = gperm((2 * i + l4) & 15), jb = gperm((2 * i + 1 + l4) & 15);
    f32x2 a, c;
    a.x = W_in[k0 * QDIM + ja];  a.y = W_in[k0 * QDIM + jb];
    c.x = W_in[k1 * QDIM + ja];  c.y = W_in[k1 * QDIM + jb];
    w0p[i] = a; w1p[i] = c;
  }

  // W_out pk pairs over (m = k0, k1), wire w = 3-B. Sign folds: chi_B for
  // B=0,1 only (B=2,3 are uniform from walsh); plus cos(theta_w) and L2E scale.
  const float L2E = 1.4426950408889634f;
  f32x2 woRpk[4], woZpk[4], woHpk[4];
#pragma unroll
  for (int B = 0; B < 4; ++B) {
    float sgn = (B <= 1) ? ((((tid >> B) & 1) ? -1.f : 1.f)) : 1.f;
    float cR = cosf(thr[3 - B])  * sgn * (-L2E);
    float cZ = cosf(thu[3 - B])  * sgn * (-L2E);
    float cH = cosf(thr1[3 - B]) * sgn * (2.f * L2E);
    float wo0 = W_out[(3 - B) * HID + k0];
    float wo1 = W_out[(3 - B) * HID + k1];
    f32x2 rr_, zz_, hh_;
    rr_.x = wo0 * cR;  rr_.y = wo1 * cR;
    zz_.x = wo0 * cZ;  zz_.y = wo1 * cZ;
    hh_.x = wo0 * cH;  hh_.y = wo1 * cH;
    woRpk[B] = rr_; woZpk[B] = zz_; woHpk[B] = hh_;
  }
  f32x2 nbcpk, bc2pk;
  nbcpk.x = -b_out[k0] * L2E;         nbcpk.y = -b_out[k1] * L2E;
  bc2pk.x =  b_out[k0] * (2.f * L2E); bc2pk.y =  b_out[k1] * (2.f * L2E);

  // tree dot: 3 dependency levels
  auto dot4pk = [](const float* e, const f32x2* w) -> f32x2 {
    f32x2 d01 = s2(e[1]) * w[1] + s2(e[0]) * w[0];
    f32x2 d23 = s2(e[3]) * w[3] + s2(e[2]) * w[2];
    return d01 + d23;
  };

  auto body = [&](auto dpc) {
    constexpr bool DP = decltype(dpc)::value;
    constexpr int C2 = DP ? 0x12C : 0x124;   // ror:12 / ror:4
    constexpr int C3 = DP ? 0x12E : 0x122;   // ror:14 / ror:2
    constexpr int C4 = DP ? 0x12F : 0x121;   // ror:15 / ror:1

    // rotation-layout reduce-scatter: v[i] = partial of column (l4+i)&15.
    // Output: full 64-lane sum for column l4, replicated in every lane.
    auto bfr = [&](const float* v) -> float {
      float w1[8];
#pragma unroll
      for (int j = 0; j < 8; ++j) w1[j] = v[j] + dpp_f<0x128>(v[j + 8]);
      float w2[4];
#pragma unroll
      for (int j = 0; j < 4; ++j) w2[j] = w1[j] + dpp_f<C2>(w1[j + 4]);
      float w3[2];
#pragma unroll
      for (int j = 0; j < 2; ++j) w3[j] = w2[j] + dpp_f<C3>(w2[j + 2]);
      float y0 = w3[0] + dpp_f<C4>(w3[1]);
      return pls32_sum(pls16_sum(y0));
    };

    f32x2 hpk; hpk.x = 0.f; hpk.y = 0.f;   // h[k0], h[k1]
    const float* pxw = xw + ((long)b * TSEQ + (dir ? TSEQ - 1 : 0)) * QDIM;
    const long xstep = dir ? -QDIM : QDIM;
    float xc = pxw[l4]; pxw += xstep;
    float xn = pxw[l4]; pxw += xstep;

    float* po  = out + (long)b * TSEQ * HID + k0;
    u32*   pbh = (u32*)bwdws + ((long)b * TSEQ * HID >> 1) + tid;

#pragma unroll 1
    for (int t = 0; t < TSEQ; ++t) {
      float xnn = pxw[l4]; pxw += xstep;   // prefetch t+2 (ws padded; overrun harmless)

      // ---- y = h @ W_h (rotated cols) + xwP ----
      f32x2 hh0 = s2(hpk.x);
      f32x2 hh1 = s2(hpk.y);
      float v[16];
#pragma unroll
      for (int i = 0; i < 8; ++i) {
        f32x2 a = hh0 * w0p[i] + hh1 * w1p[i];
        v[2 * i] = a.x; v[2 * i + 1] = a.y;
      }
      float yv = bfr(v) + xc;

      // ---- VQC1 collapsed: p[col] = yP[col]^2 ----
      float prb = yv * yv;

      float n2, eb[4];
      walsh(prb, n2, eb);
      float inv = rcpf(n2);   // n2 == |y|^2, shared by both gate types

      // gate dots (tables carry cos(theta), sign, and L2E scale)
      f32x2 rd = dot4pk(eb, woRpk);
      f32x2 zd = dot4pk(eb, woZpk);

      f32x2 ra = rd * s2(inv) + nbcpk;
      f32x2 za = zd * s2(inv) + nbcpk;
      float r0 = rcpf(1.f + ex2(ra.x));
      float r1 = rcpf(1.f + ex2(ra.y));
      float z0 = rcpf(1.f + ex2(za.x));
      float z1 = rcpf(1.f + ex2(za.y));

      // off-chain blend prep: q = z + (1-z)h ; s = -2z (ready during matvec2)
      f32x2 zpk;  zpk.x = z0; zpk.y = z1;
      f32x2 omz = s2(1.f) - zpk;
      f32x2 qpk = omz * hpk + zpk;
      f32x2 spk = s2(-2.f) * zpk;

      // ---- v1 = (r*h) @ W_h + xwP ----
      f32x2 rpk; rpk.x = r0; rpk.y = r1;
      f32x2 rh = rpk * hpk;
      hh0 = s2(rh.x);
      hh1 = s2(rh.y);
#pragma unroll
      for (int i = 0; i < 8; ++i) {
        f32x2 a = hh0 * w0p[i] + hh1 * w1p[i];
        v[2 * i] = a.x; v[2 * i + 1] = a.y;
      }
      float vv = bfr(v) + xc;

      // ---- VQC2 collapsed ----
      float prb2 = vv * vv;

      float n2b, eb2[4];
      walsh(prb2, n2b, eb2);
      float invb = rcpf(n2b);
      f32x2 hd = dot4pk(eb2, woHpk);
      f32x2 ha = hd * s2(invb) + bc2pk;
      // w = 1/(1+e^{2a}); h2 = 1-2w; hn = z*h2+(1-z)h = s*w + q
      float wq0 = rcpf(1.f + ex2(ha.x));
      float wq1 = rcpf(1.f + ex2(ha.y));
      f32x2 wpk; wpk.x = wq0; wpk.y = wq1;
      hpk = spk * wpk + qpk;

      f32x2 opk = hpk * s2(0.5f);
      if (dir == 0) {
        *reinterpret_cast<f32x2*>(po) = opk;
        po += HID;
      } else {
        u32 packed;
        asm("v_cvt_pk_bf16_f32 %0, %1, %2" : "=v"(packed) : "v"(opk.x), "v"(opk.y));
        *pbh = packed;
        pbh += HID / 2;
      }

      xc = xn; xn = xnn;
    }
  };

  if (dplus) body(std::integral_constant<bool, true>{});
  else       body(std::integral_constant<bool, false>{});
}

// ---------------- kernel 3: out += bwd trajectory (bf16 ws) ----------------

__global__ __launch_bounds__(256) void combine_k(float* __restrict__ out,
                                                 const void* __restrict__ bwd, long n4) {
  long i = (long)blockIdx.x * 256 + threadIdx.x;
  const long stride = (long)gridDim.x * 256;
  for (; i < n4; i += stride) {
    float4 o = reinterpret_cast<float4*>(out)[i];
    ushort4 u = reinterpret_cast<const ushort4*>(bwd)[i];
    o.x += __uint_as_float((u32)u.x << 16);
    o.y += __uint_as_float((u32)u.y << 16);
    o.z += __uint_as_float((u32)u.z << 16);
    o.w += __uint_as_float((u32)u.w << 16);
    reinterpret_cast<float4*>(out)[i] = o;
  }
}

// ---------------- launch ----------------

extern "C" void kernel_launch(void* const* d_in, const int* in_sizes, int n_in,
                              void* d_out, int out_size, void* d_ws, size_t ws_size,
                              hipStream_t stream) {
  const float* x     = (const float*)d_in[0];
  const float* W_in  = (const float*)d_in[1];
  const float* b_in  = (const float*)d_in[2];
  const float* W_out = (const float*)d_in[3];
  const float* b_out = (const float*)d_in[4];
  const float* thr_f  = (const float*)d_in[5];
  const float* thr1_f = (const float*)d_in[6];
  const float* thu_f  = (const float*)d_in[7];
  const float* thr_b  = (const float*)d_in[8];
  const float* thr1_b = (const float*)d_in[9];
  const float* thu_b  = (const float*)d_in[10];
  float* out = (float*)d_out;

  char* ws = (char*)d_ws;
  const size_t PAD = 4096;   // xw prefetch over/under-run guard
  const size_t xw_bytes = (size_t)NB * TSEQ * QDIM * sizeof(float);   // 8 MB
  float* xw = (float*)(ws + PAD);
  void* bwd = (void*)(ws + PAD + xw_bytes + PAD);

  xw_kernel<<<(NB * TSEQ) / 16, 256, 0, stream>>>(x, W_in, b_in, xw);

  qbigru_main<<<256, 64, 0, stream>>>(W_in, W_out, b_out,
      thr_f, thr1_f, thu_f, thr_b, thr1_b, thu_b, xw, out, bwd);

  const long n4 = (long)NB * TSEQ * HID / 4;
  combine_k<<<2048, 256, 0, stream>>>(out, bwd, n4);
}